// Round 3
// baseline (1098.639 us; speedup 1.0000x reference)
//
#include <hip/hip_runtime.h>
#include <hip/hip_bf16.h>

#define B_ 4
#define S_ 4096
#define D_ 1024
#define H_ 128

typedef unsigned short u16;
typedef unsigned int u32;

__device__ __forceinline__ float bf2f(u16 u) { return __uint_as_float(((u32)u) << 16); }
__device__ __forceinline__ float bfLo(u32 u) { return __uint_as_float(u << 16); }
__device__ __forceinline__ float bfHi(u32 u) { return __uint_as_float(u & 0xffff0000u); }
__device__ __forceinline__ u16 f2bf(float f) {
    u32 x = __float_as_uint(f);
    u32 r = x + 0x7fffu + ((x >> 16) & 1u);   // RNE
    return (u16)(r >> 16);
}

// ---------------------------------------------------------------------------
// Kernel 0: input-dtype detection (fp32 vs bf16), see round-1 notes.
// e0/e1 are the exponent fields of the two bf16 halves of each u32. For true
// bf16 weight data both are <= ~126; for fp32 data e0 is mantissa bits ->
// ~uniform, max ~255 over 2048 samples. flag=1 => fp32 inputs (and outputs).
// ---------------------------------------------------------------------------
__global__ void detect_dtype_kernel(const u32* __restrict__ w, int* __restrict__ flag) {
    __shared__ int smax[256];
    const int tid = threadIdx.x;
    int m = 0;
    for (int i = tid; i < 1024; i += 256) {
        u32 x = w[i];
        int e0 = (x >> 7) & 0xFF;
        int e1 = (x >> 23) & 0xFF;
        m = max(m, max(e0, e1));
    }
    smax[tid] = m;
    __syncthreads();
    if (tid == 0) {
        int mm = 0;
        for (int i = 0; i < 256; ++i) mm = max(mm, smax[i]);
        *flag = (mm >= 200) ? 1 : 0;
    }
}

// ---------------------------------------------------------------------------
// Kernel 1: QKV projection.  C[16384x128] = X[16384x1024] * W[1024x128]
// grid (256, 3). Q pre-scaled by 1/sqrt(128). Inputs per dtype flag; tiles
// in LDS as bf16; fp32 accumulate; bf16 Q/K/V to workspace.
// ---------------------------------------------------------------------------
__global__ __launch_bounds__(256) void qkv_kernel(
    const void* __restrict__ Xv,
    const void* __restrict__ Wqv, const void* __restrict__ Wkv, const void* __restrict__ Wvv,
    u16* __restrict__ Qo, u16* __restrict__ Ko, u16* __restrict__ Vo,
    const int* __restrict__ dflag)
{
    const int BM = 64, BK = 16;
    const void* Wv_; u16* Out; float oscale;
    if (blockIdx.y == 0)      { Wv_ = Wqv; Out = Qo; oscale = 0.08838834764831845f; }
    else if (blockIdx.y == 1) { Wv_ = Wkv; Out = Ko; oscale = 1.0f; }
    else                      { Wv_ = Wvv; Out = Vo; oscale = 1.0f; }

    const int isf32 = *dflag;   // block-uniform scalar branch

    __shared__ u16 Ast[BK][BM + 8];   // A^T tile (k-major)
    __shared__ u16 Bs[BK][H_];        // 16x128 bf16

    const int tid = threadIdx.x;
    const int ty = tid >> 4;          // rows ty*4 .. ty*4+3
    const int tx = tid & 15;          // cols tx*8 .. tx*8+7
    const size_t m0 = (size_t)blockIdx.x * BM;

    float acc[4][8];
#pragma unroll
    for (int r = 0; r < 4; ++r)
#pragma unroll
        for (int c = 0; c < 8; ++c) acc[r][c] = 0.f;

    const int ar = (tid * 4) >> 4;    // 0..63
    const int ac = (tid * 4) & 15;    // {0,4,8,12}
    const int br = (tid * 8) >> 7;    // 0..15
    const int bc = (tid * 8) & 127;

    for (int k0 = 0; k0 < D_; k0 += BK) {
        if (isf32) {
            float4 a = *(const float4*)((const float*)Xv + (m0 + ar) * D_ + k0 + ac);
            Ast[ac + 0][ar] = f2bf(a.x);
            Ast[ac + 1][ar] = f2bf(a.y);
            Ast[ac + 2][ar] = f2bf(a.z);
            Ast[ac + 3][ar] = f2bf(a.w);
            const float* wp = (const float*)Wv_ + (size_t)(k0 + br) * H_ + bc;
            float4 b0 = *(const float4*)wp;
            float4 b1 = *(const float4*)(wp + 4);
            union { u16 u[8]; uint4 v; } pk;
            pk.u[0] = f2bf(b0.x); pk.u[1] = f2bf(b0.y);
            pk.u[2] = f2bf(b0.z); pk.u[3] = f2bf(b0.w);
            pk.u[4] = f2bf(b1.x); pk.u[5] = f2bf(b1.y);
            pk.u[6] = f2bf(b1.z); pk.u[7] = f2bf(b1.w);
            *(uint4*)&Bs[br][bc] = pk.v;
        } else {
            ushort4 av = *(const ushort4*)((const u16*)Xv + (m0 + ar) * D_ + k0 + ac);
            Ast[ac + 0][ar] = av.x;
            Ast[ac + 1][ar] = av.y;
            Ast[ac + 2][ar] = av.z;
            Ast[ac + 3][ar] = av.w;
            *(uint4*)&Bs[br][bc] = *(const uint4*)((const u16*)Wv_ + (size_t)(k0 + br) * H_ + bc);
        }
        __syncthreads();
#pragma unroll 4
        for (int k = 0; k < BK; ++k) {
            ushort4 a4 = *(const ushort4*)&Ast[k][ty * 4];
            float a0 = bf2f(a4.x), a1 = bf2f(a4.y), a2 = bf2f(a4.z), a3 = bf2f(a4.w);
            uint4 b4 = *(const uint4*)&Bs[k][tx * 8];
            float b[8];
            b[0] = bfLo(b4.x); b[1] = bfHi(b4.x);
            b[2] = bfLo(b4.y); b[3] = bfHi(b4.y);
            b[4] = bfLo(b4.z); b[5] = bfHi(b4.z);
            b[6] = bfLo(b4.w); b[7] = bfHi(b4.w);
#pragma unroll
            for (int c = 0; c < 8; ++c) {
                acc[0][c] += a0 * b[c];
                acc[1][c] += a1 * b[c];
                acc[2][c] += a2 * b[c];
                acc[3][c] += a3 * b[c];
            }
        }
        __syncthreads();
    }
#pragma unroll
    for (int r = 0; r < 4; ++r) {
        union { u16 u[8]; uint4 v; } pk;
#pragma unroll
        for (int c = 0; c < 8; ++c) pk.u[c] = f2bf(acc[r][c] * oscale);
        *(uint4*)(Out + (m0 + ty * 4 + r) * H_ + tx * 8) = pk.v;
    }
}

// ---------------------------------------------------------------------------
// Kernel 2: causal flash attention over bf16 Q/K/V from workspace.
// grid (64, 4). Output dtype per flag: fp32 (flag=1) or bf16 (flag=0).
// ---------------------------------------------------------------------------
__global__ __launch_bounds__(256) void attn_kernel(
    const u16* __restrict__ Q, const u16* __restrict__ K, const u16* __restrict__ V,
    void* __restrict__ out, const int* __restrict__ dflag)
{
    const int QT = 64, KT = 64;
    __shared__ u16 Qs[QT][H_ + 8];
    __shared__ u16 KVs[KT][H_ + 8];
    __shared__ float Ss[QT][KT + 4];
    __shared__ float mrow[QT], lrow[QT], arow[QT];

    const int tid = threadIdx.x;
    const int qt  = blockIdx.x;
    const int b   = blockIdx.y;
    const int ty  = tid >> 4;
    const int tx  = tid & 15;

    const u16* Qg = Q + ((size_t)b * S_ + (size_t)qt * QT) * H_;
    const u16* Kg = K + (size_t)b * S_ * H_;
    const u16* Vg = V + (size_t)b * S_ * H_;

#pragma unroll
    for (int t = 0; t < 4; ++t) {
        int i = tid + t * 256;
        int row = i >> 4, col = (i & 15) * 8;
        *(uint4*)&Qs[row][col] = *(const uint4*)(Qg + (size_t)row * H_ + col);
    }
    if (tid < QT) { mrow[tid] = -1e30f; lrow[tid] = 0.f; }

    float O[4][8];
#pragma unroll
    for (int r = 0; r < 4; ++r)
#pragma unroll
        for (int c = 0; c < 8; ++c) O[r][c] = 0.f;

    for (int j = 0; j <= qt; ++j) {
        __syncthreads();
#pragma unroll
        for (int t = 0; t < 4; ++t) {
            int i = tid + t * 256;
            int row = i >> 4, col = (i & 15) * 8;
            *(uint4*)&KVs[row][col] = *(const uint4*)(Kg + ((size_t)j * KT + row) * H_ + col);
        }
        __syncthreads();

        float s[4][4];
#pragma unroll
        for (int r = 0; r < 4; ++r)
#pragma unroll
            for (int c = 0; c < 4; ++c) s[r][c] = 0.f;

        for (int k = 0; k < H_; k += 8) {
            float qf[4][8], kf[4][8];
#pragma unroll
            for (int r = 0; r < 4; ++r) {
                uint4 v = *(const uint4*)&Qs[ty + 16 * r][k];
                qf[r][0] = bfLo(v.x); qf[r][1] = bfHi(v.x);
                qf[r][2] = bfLo(v.y); qf[r][3] = bfHi(v.y);
                qf[r][4] = bfLo(v.z); qf[r][5] = bfHi(v.z);
                qf[r][6] = bfLo(v.w); qf[r][7] = bfHi(v.w);
            }
#pragma unroll
            for (int c = 0; c < 4; ++c) {
                uint4 v = *(const uint4*)&KVs[tx + 16 * c][k];
                kf[c][0] = bfLo(v.x); kf[c][1] = bfHi(v.x);
                kf[c][2] = bfLo(v.y); kf[c][3] = bfHi(v.y);
                kf[c][4] = bfLo(v.z); kf[c][5] = bfHi(v.z);
                kf[c][6] = bfLo(v.w); kf[c][7] = bfHi(v.w);
            }
#pragma unroll
            for (int r = 0; r < 4; ++r)
#pragma unroll
                for (int c = 0; c < 4; ++c) {
                    float a = s[r][c];
#pragma unroll
                    for (int t = 0; t < 8; ++t) a += qf[r][t] * kf[c][t];
                    s[r][c] = a;
                }
        }

        if (j == qt) {
#pragma unroll
            for (int r = 0; r < 4; ++r)
#pragma unroll
                for (int c = 0; c < 4; ++c)
                    if ((tx + 16 * c) > (ty + 16 * r)) s[r][c] = -1e30f;
        }
#pragma unroll
        for (int r = 0; r < 4; ++r)
#pragma unroll
            for (int c = 0; c < 4; ++c)
                Ss[ty + 16 * r][tx + 16 * c] = s[r][c];
        __syncthreads();

#pragma unroll
        for (int t = 0; t < 4; ++t) {
            int i = tid + t * 256;
            int row = i >> 4, col = (i & 15) * 8;
            *(uint4*)&KVs[row][col] = *(const uint4*)(Vg + ((size_t)j * KT + row) * H_ + col);
        }
        if (tid < QT) {
            float mold = mrow[tid];
            float m = mold;
            for (int k2 = 0; k2 < KT; ++k2) m = fmaxf(m, Ss[tid][k2]);
            float l = 0.f;
            for (int k2 = 0; k2 < KT; ++k2) {
                float p = __expf(Ss[tid][k2] - m);
                Ss[tid][k2] = p;
                l += p;
            }
            float alpha = __expf(mold - m);
            mrow[tid] = m;
            arow[tid] = alpha;
            lrow[tid] = lrow[tid] * alpha + l;
        }
        __syncthreads();

        float al[4];
#pragma unroll
        for (int r = 0; r < 4; ++r) al[r] = arow[ty + 16 * r];
#pragma unroll
        for (int r = 0; r < 4; ++r)
#pragma unroll
            for (int c = 0; c < 8; ++c) O[r][c] *= al[r];

        for (int kk = 0; kk < KT; kk += 4) {
            float vv[4][8];
#pragma unroll
            for (int t = 0; t < 4; ++t) {
                uint4 v = *(const uint4*)&KVs[kk + t][tx * 8];
                vv[t][0] = bfLo(v.x); vv[t][1] = bfHi(v.x);
                vv[t][2] = bfLo(v.y); vv[t][3] = bfHi(v.y);
                vv[t][4] = bfLo(v.z); vv[t][5] = bfHi(v.z);
                vv[t][6] = bfLo(v.w); vv[t][7] = bfHi(v.w);
            }
#pragma unroll
            for (int r = 0; r < 4; ++r) {
                float4 p = *(const float4*)&Ss[ty + 16 * r][kk];
#pragma unroll
                for (int c = 0; c < 8; ++c)
                    O[r][c] += p.x * vv[0][c] + p.y * vv[1][c] + p.z * vv[2][c] + p.w * vv[3][c];
            }
        }
    }

    float linv[4];
#pragma unroll
    for (int r = 0; r < 4; ++r) linv[r] = 1.0f / lrow[ty + 16 * r];

    const size_t rowbase = (size_t)b * S_ + (size_t)qt * QT;
    if (*dflag) {
        float* of = (float*)out;
#pragma unroll
        for (int r = 0; r < 4; ++r) {
            float4 lo, hi;
            lo.x = O[r][0] * linv[r]; lo.y = O[r][1] * linv[r];
            lo.z = O[r][2] * linv[r]; lo.w = O[r][3] * linv[r];
            hi.x = O[r][4] * linv[r]; hi.y = O[r][5] * linv[r];
            hi.z = O[r][6] * linv[r]; hi.w = O[r][7] * linv[r];
            float* p = of + (rowbase + ty + 16 * r) * H_ + tx * 8;
            *(float4*)p = lo;
            *(float4*)(p + 4) = hi;
        }
    } else {
        u16* ob = (u16*)out;
#pragma unroll
        for (int r = 0; r < 4; ++r) {
            union { u16 u[8]; uint4 v; } pk;
#pragma unroll
            for (int c = 0; c < 8; ++c) pk.u[c] = f2bf(O[r][c] * linv[r]);
            *(uint4*)(ob + (rowbase + ty + 16 * r) * H_ + tx * 8) = pk.v;
        }
    }
}

extern "C" void kernel_launch(void* const* d_in, const int* in_sizes, int n_in,
                              void* d_out, int out_size, void* d_ws, size_t ws_size,
                              hipStream_t stream) {
    (void)in_sizes; (void)n_in; (void)out_size; (void)ws_size;
    const void* X  = d_in[0];
    const void* Wq = d_in[1];
    const void* Wk = d_in[2];
    const void* Wv = d_in[3];

    int* dflag = (int*)d_ws;                         // 256-byte header
    u16* Qw = (u16*)((char*)d_ws + 256);
    const size_t n = (size_t)B_ * S_ * H_;           // 2M elements per tensor
    u16* Kw = Qw + n;
    u16* Vw = Kw + n;

    detect_dtype_kernel<<<1, 256, 0, stream>>>((const u32*)Wq, dflag);
    qkv_kernel<<<dim3((B_ * S_) / 64, 3), 256, 0, stream>>>(X, Wq, Wk, Wv, Qw, Kw, Vw, dflag);
    attn_kernel<<<dim3(S_ / 64, B_), 256, 0, stream>>>(Qw, Kw, Vw, d_out, dflag);
}

// Round 4
// 373.507 us; speedup vs baseline: 2.9414x; 2.9414x over previous
//
#include <hip/hip_runtime.h>
#include <hip/hip_bf16.h>

#define B_ 4
#define S_ 4096
#define D_ 1024
#define H_ 128

typedef unsigned short u16;
typedef unsigned int u32;
typedef short s16x8 __attribute__((ext_vector_type(8)));   // 8 bf16 (4 VGPRs)
typedef float f32x4 __attribute__((ext_vector_type(4)));   // MFMA 16x16 acc

__device__ __forceinline__ float bf2f(u16 u) { return __uint_as_float(((u32)u) << 16); }
__device__ __forceinline__ u16 f2bf(float f) {
    u32 x = __float_as_uint(f);
    u32 r = x + 0x7fffu + ((x >> 16) & 1u);   // RNE
    return (u16)(r >> 16);
}

// ---------------------------------------------------------------------------
// Kernel 0: input dtype detection (fp32 vs bf16). Verified in round 3.
// ---------------------------------------------------------------------------
__global__ void detect_dtype_kernel(const u32* __restrict__ w, int* __restrict__ flag) {
    __shared__ int smax[256];
    const int tid = threadIdx.x;
    int m = 0;
    for (int i = tid; i < 1024; i += 256) {
        u32 x = w[i];
        m = max(m, max((int)((x >> 7) & 0xFF), (int)((x >> 23) & 0xFF)));
    }
    smax[tid] = m;
    __syncthreads();
    if (tid == 0) {
        int mm = 0;
        for (int i = 0; i < 256; ++i) mm = max(mm, smax[i]);
        *flag = (mm >= 200) ? 1 : 0;
    }
}

// ---------------------------------------------------------------------------
// Kernel 0b: W -> Wt, bf16, transposed + tiled for MFMA B-fragment reads.
// Wt layout: tile (mat, kt) is 128n x 32k contiguous: offset
//   ((mat*32 + kt)*128 + n)*32 + (k % 32). Lane B-frag read is then 16B
//   contiguous in k. grid (32 kt, 3 mat), 256 threads.
// ---------------------------------------------------------------------------
__global__ __launch_bounds__(256) void prep_w_kernel(
    const void* __restrict__ Wq, const void* __restrict__ Wk, const void* __restrict__ Wv,
    u16* __restrict__ Wt, const int* __restrict__ dflag)
{
    const int kt = blockIdx.x, mat = blockIdx.y;
    const void* W = (mat == 0) ? Wq : (mat == 1) ? Wk : Wv;
    const int isf = *dflag;
    const int t = threadIdx.x;
    const int kk = t >> 3;            // 0..31 (k within tile)
    const int n0 = (t & 7) * 16;      // 16 n per thread
    u16 vals[16];
    if (isf) {
        const float* wp = (const float*)W + (size_t)(kt * 32 + kk) * H_ + n0;
#pragma unroll
        for (int i = 0; i < 16; ++i) vals[i] = f2bf(wp[i]);
    } else {
        const u16* wp = (const u16*)W + (size_t)(kt * 32 + kk) * H_ + n0;
#pragma unroll
        for (int i = 0; i < 16; ++i) vals[i] = wp[i];
    }
    const size_t base = (size_t)(mat * 32 + kt) * 128;
#pragma unroll
    for (int i = 0; i < 16; ++i)
        Wt[(base + n0 + i) * 32 + kk] = vals[i];
}

// ---------------------------------------------------------------------------
// Kernel 1: fused QKV GEMM via MFMA 16x16x32 bf16.
// [16384 x 1024] X times 3x[1024 x 128] W in one pass over X.
// grid 256 blocks (BM=64), 256 threads = 4 waves; wave w owns rows w*16..+15.
// Per BK=32 tile: 1 A-frag read + 24 B-frag reads + 24 MFMAs per wave.
// Q pre-scaled by 1/sqrt(128). Outputs bf16 to workspace.
// A-frag: A[m=lane&15][k=q*8+j]; B-frag: B[k=q*8+j][n=lane&15];
// C/D: row=q*4+reg, col=lane&15  (m89-verified layouts).
// ---------------------------------------------------------------------------
__global__ __launch_bounds__(256) void qkv_kernel(
    const void* __restrict__ Xv, const u16* __restrict__ Wt,
    u16* __restrict__ Qo, u16* __restrict__ Ko, u16* __restrict__ Vo,
    const int* __restrict__ dflag)
{
    __shared__ u16 Xs[64 * 40];     // 64 rows x 32 k, stride 40 (+8 pad: 2-way max)
    __shared__ u16 Ws[384 * 40];    // 3*128 n-rows x 32 k, stride 40
    __shared__ u16 Os[64 * 136];    // epilogue bounce, one matrix at a time

    const int isf = *dflag;
    const int tid = threadIdx.x;
    const int w = tid >> 6, lane = tid & 63;
    const int r = lane & 15, q = lane >> 4;
    const size_t m0 = (size_t)blockIdx.x * 64;

    f32x4 acc[3][8];
#pragma unroll
    for (int m = 0; m < 3; ++m)
#pragma unroll
        for (int nt = 0; nt < 8; ++nt) acc[m][nt] = (f32x4){0.f, 0.f, 0.f, 0.f};

    const int xr = tid >> 2, xo = tid & 3;   // X stage: row, k-octet

    for (int kt = 0; kt < 32; ++kt) {
        const int k0 = kt * 32;
        // stage X tile (fp32->bf16 or bf16 passthrough)
        if (isf) {
            const float* xp = (const float*)Xv + (m0 + xr) * D_ + k0 + xo * 8;
            float4 a = *(const float4*)xp, b2 = *(const float4*)(xp + 4);
            union { u16 u[8]; uint4 v; } pk;
            pk.u[0] = f2bf(a.x);  pk.u[1] = f2bf(a.y);
            pk.u[2] = f2bf(a.z);  pk.u[3] = f2bf(a.w);
            pk.u[4] = f2bf(b2.x); pk.u[5] = f2bf(b2.y);
            pk.u[6] = f2bf(b2.z); pk.u[7] = f2bf(b2.w);
            *(uint4*)&Xs[xr * 40 + xo * 8] = pk.v;
        } else {
            *(uint4*)&Xs[xr * 40 + xo * 8] =
                *(const uint4*)((const u16*)Xv + (m0 + xr) * D_ + k0 + xo * 8);
        }
        // stage W tiles for all 3 matrices (coalesced linear from Wt)
#pragma unroll
        for (int i = 0; i < 6; ++i) {
            int c = tid + i * 256;              // 1536 16B chunks
            int row = c >> 2, part = c & 3;     // row 0..383
            int mat = row >> 7, nn = row & 127;
            *(uint4*)&Ws[row * 40 + part * 8] =
                *(const uint4*)(Wt + ((size_t)(mat * 32 + kt) * 128 + nn) * 32 + part * 8);
        }
        __syncthreads();

        s16x8 a = *(const s16x8*)&Xs[(w * 16 + r) * 40 + q * 8];
#pragma unroll
        for (int m = 0; m < 3; ++m)
#pragma unroll
            for (int nt = 0; nt < 8; ++nt) {
                s16x8 b = *(const s16x8*)&Ws[(m * 128 + nt * 16 + r) * 40 + q * 8];
                acc[m][nt] = __builtin_amdgcn_mfma_f32_16x16x32_bf16(a, b, acc[m][nt], 0, 0, 0);
            }
        __syncthreads();
    }

    // epilogue: LDS bounce per matrix, then coalesced bf16 stores
    u16* outs[3] = {Qo, Ko, Vo};
    for (int m = 0; m < 3; ++m) {
        const float sc = (m == 0) ? 0.08838834764831845f : 1.0f;
#pragma unroll
        for (int nt = 0; nt < 8; ++nt)
#pragma unroll
            for (int reg = 0; reg < 4; ++reg)
                Os[(w * 16 + q * 4 + reg) * 136 + nt * 16 + r] = f2bf(acc[m][nt][reg] * sc);
        __syncthreads();
        u16* Out = outs[m];
#pragma unroll
        for (int i = 0; i < 4; ++i) {
            int c = tid + i * 256;
            int row = c >> 4, col = (c & 15) * 8;
            *(uint4*)(Out + (m0 + row) * H_ + col) = *(const uint4*)&Os[row * 136 + col];
        }
        __syncthreads();
    }
}

// ---------------------------------------------------------------------------
// Kernel 2: causal flash attention via MFMA. QT=32, KT=64.
// grid (64, 4): block p handles q-tiles {p, 127-p} -> constant 65 K-tiles
// per block (perfect causal load balance). 256 threads = 4 waves.
// Wave w: S-tile rows (w&1)*16, keys (w>>1)*32; O rows (w&1)*16, h (w>>1)*64.
// V staged transposed (Vt[h][k]) so PV B-frags are contiguous b128.
// S -> LDS fp32 (C-layout) -> softmax (shfl row-reduce) -> bf16 P (A-layout).
// ---------------------------------------------------------------------------
__global__ __launch_bounds__(256) void attn_kernel(
    const u16* __restrict__ Q, const u16* __restrict__ K, const u16* __restrict__ V,
    void* __restrict__ out, const int* __restrict__ dflag)
{
    __shared__ u16 Qs[32 * 136];
    __shared__ union { u16 ks[64 * 136]; float of[32 * 132]; } KU;  // K tile / O bounce
    __shared__ u16 Vt[128 * 72];
    __shared__ float Sf[32 * 68];
    __shared__ u16 Ps[32 * 72];
    __shared__ float mrow[32], lrow[32], arow[32];

    const int isf = *dflag;
    const int tid = threadIdx.x;
    const int w = tid >> 6, lane = tid & 63;
    const int r = lane & 15, q = lane >> 4;
    const int b = blockIdx.y;
    const int mw = w & 1;            // S/O row-tile of this wave
    const int nb = (w >> 1) * 2;     // S key-tile pair
    const int hb = (w >> 1) * 4;     // O h-tile quad
    const int srow = tid >> 3, sseg = tid & 7;   // softmax map: 8 threads/row

    const u16* Kg = K + (size_t)b * S_ * H_;
    const u16* Vg = V + (size_t)b * S_ * H_;

    for (int pass = 0; pass < 2; ++pass) {
        const int qt = pass ? (127 - blockIdx.x) : blockIdx.x;
        const u16* Qg = Q + ((size_t)b * S_ + (size_t)qt * 32) * H_;
#pragma unroll
        for (int i = 0; i < 2; ++i) {
            int c = tid + i * 256;
            int row = c >> 4, col = (c & 15) * 8;
            *(uint4*)&Qs[row * 136 + col] = *(const uint4*)(Qg + (size_t)row * H_ + col);
        }
        if (tid < 32) { mrow[tid] = -1e30f; lrow[tid] = 0.f; }

        f32x4 accO[4];
#pragma unroll
        for (int ht = 0; ht < 4; ++ht) accO[ht] = (f32x4){0.f, 0.f, 0.f, 0.f};

        const int nKT = (qt + 2) >> 1;
        for (int j = 0; j < nKT; ++j) {
            __syncthreads();   // prev iter done with KU.ks/Vt; Qs/state ready (j==0)
#pragma unroll
            for (int i = 0; i < 4; ++i) {
                int c = tid + i * 256;
                int row = c >> 4, col = (c & 15) * 8;
                *(uint4*)&KU.ks[row * 136 + col] =
                    *(const uint4*)(Kg + ((size_t)j * 64 + row) * H_ + col);
            }
#pragma unroll
            for (int i = 0; i < 4; ++i) {
                int c = tid + i * 256;
                int row = c >> 4, colb = (c & 15) * 8;
                union { u16 u[8]; uint4 v; } pk;
                pk.v = *(const uint4*)(Vg + ((size_t)j * 64 + row) * H_ + colb);
#pragma unroll
                for (int e = 0; e < 8; ++e)
                    Vt[(colb + e) * 72 + row] = pk.u[e];
            }
            __syncthreads();

            // ---- S = Q K^T (Q pre-scaled) ----
            f32x4 accS[2];
            accS[0] = (f32x4){0.f, 0.f, 0.f, 0.f};
            accS[1] = (f32x4){0.f, 0.f, 0.f, 0.f};
#pragma unroll
            for (int ks = 0; ks < 4; ++ks) {
                s16x8 a = *(const s16x8*)&Qs[(mw * 16 + r) * 136 + ks * 32 + q * 8];
#pragma unroll
                for (int t2 = 0; t2 < 2; ++t2) {
                    s16x8 bb = *(const s16x8*)&KU.ks[((nb + t2) * 16 + r) * 136 + ks * 32 + q * 8];
                    accS[t2] = __builtin_amdgcn_mfma_f32_16x16x32_bf16(a, bb, accS[t2], 0, 0, 0);
                }
            }
#pragma unroll
            for (int t2 = 0; t2 < 2; ++t2)
#pragma unroll
                for (int reg = 0; reg < 4; ++reg)
                    Sf[(mw * 16 + q * 4 + reg) * 68 + (nb + t2) * 16 + r] = accS[t2][reg];
            __syncthreads();

            // ---- online softmax (8 threads per row, wave-synchronous) ----
            {
                float4 s0 = *(const float4*)&Sf[srow * 68 + sseg * 8];
                float4 s1 = *(const float4*)&Sf[srow * 68 + sseg * 8 + 4];
                float sv[8] = {s0.x, s0.y, s0.z, s0.w, s1.x, s1.y, s1.z, s1.w};
                if (j == nKT - 1) {   // only the last tile can cross the diagonal
                    int grow = qt * 32 + srow;
#pragma unroll
                    for (int i = 0; i < 8; ++i)
                        if (j * 64 + sseg * 8 + i > grow) sv[i] = -1e30f;
                }
                float m8 = sv[0];
#pragma unroll
                for (int i = 1; i < 8; ++i) m8 = fmaxf(m8, sv[i]);
                m8 = fmaxf(m8, __shfl_xor(m8, 1));
                m8 = fmaxf(m8, __shfl_xor(m8, 2));
                m8 = fmaxf(m8, __shfl_xor(m8, 4));
                float mold = mrow[srow];
                float mnew = fmaxf(mold, m8);
                float psum = 0.f;
                union { u16 u[8]; uint4 v; } pk;
#pragma unroll
                for (int i = 0; i < 8; ++i) {
                    float p = __expf(sv[i] - mnew);
                    psum += p;
                    pk.u[i] = f2bf(p);
                }
                *(uint4*)&Ps[srow * 72 + sseg * 8] = pk.v;
                psum += __shfl_xor(psum, 1);
                psum += __shfl_xor(psum, 2);
                psum += __shfl_xor(psum, 4);
                if (sseg == 0) {
                    float alpha = __expf(mold - mnew);
                    mrow[srow] = mnew;
                    arow[srow] = alpha;
                    lrow[srow] = lrow[srow] * alpha + psum;
                }
            }
            __syncthreads();

            // ---- O = O*alpha + P V ----
            float alr[4];
#pragma unroll
            for (int reg = 0; reg < 4; ++reg) alr[reg] = arow[mw * 16 + q * 4 + reg];
#pragma unroll
            for (int ht = 0; ht < 4; ++ht)
#pragma unroll
                for (int reg = 0; reg < 4; ++reg) accO[ht][reg] *= alr[reg];
#pragma unroll
            for (int ks = 0; ks < 2; ++ks) {
                s16x8 a = *(const s16x8*)&Ps[(mw * 16 + r) * 72 + ks * 32 + q * 8];
#pragma unroll
                for (int ht = 0; ht < 4; ++ht) {
                    s16x8 bb = *(const s16x8*)&Vt[((hb + ht) * 16 + r) * 72 + ks * 32 + q * 8];
                    accO[ht] = __builtin_amdgcn_mfma_f32_16x16x32_bf16(a, bb, accO[ht], 0, 0, 0);
                }
            }
        }

        // ---- epilogue: normalize, bounce via LDS, coalesced store ----
        float linv[4];
#pragma unroll
        for (int reg = 0; reg < 4; ++reg) linv[reg] = 1.0f / lrow[mw * 16 + q * 4 + reg];
#pragma unroll
        for (int ht = 0; ht < 4; ++ht)
#pragma unroll
            for (int reg = 0; reg < 4; ++reg)
                KU.of[(mw * 16 + q * 4 + reg) * 132 + (hb + ht) * 16 + r] = accO[ht][reg] * linv[reg];
        __syncthreads();
        {
            const size_t obase = (size_t)b * S_ + (size_t)qt * 32;
            int row = tid >> 3, col = (tid & 7) * 16;
            const float* src = &KU.of[row * 132 + col];
            if (isf) {
                float* dst = (float*)out + (obase + row) * H_ + col;
#pragma unroll
                for (int i = 0; i < 4; ++i)
                    *(float4*)(dst + i * 4) = *(const float4*)(src + i * 4);
            } else {
                u16* dst = (u16*)out + (obase + row) * H_ + col;
#pragma unroll
                for (int hh = 0; hh < 2; ++hh) {
                    union { u16 u[8]; uint4 v; } pk;
#pragma unroll
                    for (int i = 0; i < 8; ++i) pk.u[i] = f2bf(src[hh * 8 + i]);
                    *(uint4*)(dst + hh * 8) = pk.v;
                }
            }
        }
        __syncthreads();   // protect KU/Qs/state before next pass restage
    }
}

extern "C" void kernel_launch(void* const* d_in, const int* in_sizes, int n_in,
                              void* d_out, int out_size, void* d_ws, size_t ws_size,
                              hipStream_t stream) {
    (void)in_sizes; (void)n_in; (void)out_size; (void)ws_size;
    const void* X  = d_in[0];
    const void* Wq = d_in[1];
    const void* Wk = d_in[2];
    const void* Wv = d_in[3];

    int* dflag = (int*)d_ws;                          // 256 B header
    u16* Qw = (u16*)((char*)d_ws + 256);
    const size_t n = (size_t)B_ * S_ * H_;            // 2M elems per tensor
    u16* Kw = Qw + n;
    u16* Vw = Kw + n;
    u16* Wt = Vw + n;                                 // 3*1024*128 bf16 = 768 KB

    detect_dtype_kernel<<<1, 256, 0, stream>>>((const u32*)Wq, dflag);
    prep_w_kernel<<<dim3(32, 3), 256, 0, stream>>>(Wq, Wk, Wv, Wt, dflag);
    qkv_kernel<<<256, 256, 0, stream>>>(X, Wt, Qw, Kw, Vw, dflag);
    attn_kernel<<<dim3(64, B_), 256, 0, stream>>>(Qw, Kw, Vw, d_out, dflag);
}